// Round 8
// baseline (475.850 us; speedup 1.0000x reference)
//
#include <hip/hip_runtime.h>

// ---------------------------------------------------------------------------
// GNN_20237885899323: 2-layer GCN + mean-pool + MLP head, all fp32.
// Round 8: rounds 6/7 proved the gather kernels sit at a random-line L2-miss
// service bound (~3.5 TB/s, unroll-invariant). This round: (1) non-temporal
// hints so once-streamed srcIdx/pairBuf/z2 stop evicting gather rows from the
// 4MB per-XCD L2s; (2) fold bucketScan + node_init into passB (8->6 launches;
// h~0 gets a DEDICATED buffer since passB's epilogue would race with other
// blocks' unread pairBuf regions if aliased); (3) poolhead 512 thr + w2 in LDS.
// ---------------------------------------------------------------------------

typedef float vfloat4 __attribute__((ext_vector_type(4)));

#define NBMAX 512
#define BCAP 12288
#define CAPL 10240

__global__ void k_initcur(int* __restrict__ bcur) {
    bcur[threadIdx.x] = threadIdx.x * BCAP;  // 512 threads
}

__global__ void k_passA(const int* __restrict__ ei, int* __restrict__ bcur,
                        unsigned int* __restrict__ pairBuf, int E) {
    __shared__ int h[NBMAX];
    __shared__ int base[NBMAX];
    const int T = 256, EPT = 32;
    int chunk = blockIdx.x * (T * EPT);
    int t = threadIdx.x;
    h[t] = 0; h[t + 256] = 0;
    __syncthreads();
    int nE = min(E - chunk, T * EPT);
    for (int i = t; i < nE; i += T)
        atomicAdd(&h[ei[E + chunk + i] >> 8], 1);
    __syncthreads();
    for (int bb = t; bb < NBMAX; bb += T) {
        int c = h[bb];
        base[bb] = c > 0 ? atomicAdd(&bcur[bb], c) : 0;
        h[bb] = 0;
    }
    __syncthreads();
    for (int i = t; i < nE; i += T) {
        int s = ei[chunk + i];
        int d = ei[E + chunk + i];
        int bb = d >> 8;
        int pos = base[bb] + atomicAdd(&h[bb], 1);
        __builtin_nontemporal_store(((unsigned int)(d & 255) << 24) | (unsigned int)s,
                                    pairBuf + pos);
    }
}

__global__ void k_passB(const int* __restrict__ bcur,
                        const unsigned int* __restrict__ pairBuf,
                        int* __restrict__ rowPtr, float* __restrict__ dis,
                        int* __restrict__ srcIdx, const float* __restrict__ x,
                        const float* __restrict__ wn, const float* __restrict__ bn,
                        float* __restrict__ h0, int N, int E) {
    __shared__ unsigned int eLds[CAPL];
    __shared__ int hist[256];
    __shared__ int scan[256];
    __shared__ float disL[256];
    __shared__ float wsh[64];
    __shared__ float bsh[32];
    int b = blockIdx.x;
    int t = threadIdx.x;  // 256
    int count = bcur[b] - b * BCAP;
    const unsigned int* src = pairBuf + (size_t)b * BCAP;
    int part = 0;
    for (int i = t; i < b; i += 256) part += bcur[i] - i * BCAP;
    scan[t] = part;
    __syncthreads();
    for (int o = 128; o > 0; o >>= 1) {
        if (t < o) scan[t] += scan[t + o];
        __syncthreads();
    }
    int gbase = scan[0];
    __syncthreads();
    hist[t] = 0;
    if (t < 64) wsh[t] = wn[t];
    if (t < 32) bsh[t] = bn[t];
    int nStage = min(count, CAPL);
    for (int i = t; i < nStage; i += 256) eLds[i] = __builtin_nontemporal_load(src + i);
    __syncthreads();
    for (int i = t; i < nStage; i += 256) atomicAdd(&hist[eLds[i] >> 24], 1);
    for (int i = CAPL + t; i < count; i += 256)
        atomicAdd(&hist[__builtin_nontemporal_load(src + i) >> 24], 1);
    __syncthreads();
    int c = hist[t];
    scan[t] = c;
    __syncthreads();
    for (int o = 1; o < 256; o <<= 1) {
        int v = (t >= o) ? scan[t - o] : 0;
        __syncthreads();
        scan[t] += v;
        __syncthreads();
    }
    int excl = scan[t] - c;
    int node = (b << 8) + t;
    float dval = rsqrtf((float)c + 1.0f);
    disL[t] = dval;
    if (node < N) {
        rowPtr[node] = gbase + excl;
        dis[node] = dval;
        if (node == N - 1) rowPtr[N] = E;
    }
    hist[t] = excl;
    __syncthreads();
    for (int i = t; i < nStage; i += 256) {
        unsigned int e = eLds[i];
        int pos = atomicAdd(&hist[e >> 24], 1);
        __builtin_nontemporal_store((int)(e & 0xFFFFFFu), srcIdx + gbase + pos);
    }
    for (int i = CAPL + t; i < count; i += 256) {
        unsigned int e = __builtin_nontemporal_load(src + i);
        int pos = atomicAdd(&hist[e >> 24], 1);
        __builtin_nontemporal_store((int)(e & 0xFFFFFFu), srcIdx + gbase + pos);
    }
    __syncthreads();
    for (int ch = 0; ch < 32; ++ch) {
        int ln = ch * 8 + (t >> 5);
        int f = t & 31;
        int n2 = (b << 8) + ln;
        if (n2 < N) {
            float v = x[2 * n2] * wsh[f] + x[2 * n2 + 1] * wsh[32 + f] + bsh[f];
            v = fmaxf(v, 0.f);
            h0[(size_t)n2 * 32 + f] = v * disL[ln];
        }
    }
}

__global__ void k_agg32mm(const int* __restrict__ rowPtr, const int* __restrict__ srcIdx,
                          const float* __restrict__ y, const float* __restrict__ dis,
                          const float* __restrict__ w1, const float* __restrict__ b1,
                          float* __restrict__ hOut, int N) {
    constexpr int QF = 8, RPI = 8, U = 4, CH = RPI * U;
    int wid = (blockIdx.x * blockDim.x + threadIdx.x) >> 6;
    if (wid >= N) return;
    int lane = threadIdx.x & 63;
    int q = lane & (QF - 1);
    int r = lane / QF;
    int beg = rowPtr[wid], end = rowPtr[wid + 1];
    const float4* yq = (const float4*)y;
    float4 acc = {0.f, 0.f, 0.f, 0.f};
    if (r == 0) acc = yq[(size_t)wid * QF + q];
    if (end > beg) {
        int last = end - 1;
        for (int base = beg; base < end; base += CH) {
            int s[U];
            float m[U];
#pragma unroll
            for (int u = 0; u < U; ++u) {
                int i = base + r + u * RPI;
                m[u] = (i < end) ? 1.f : 0.f;
                s[u] = __builtin_nontemporal_load(srcIdx + min(i, last));
            }
#pragma unroll
            for (int u = 0; u < U; ++u) {
                float4 a = yq[(size_t)s[u] * QF + q];
                acc.x = fmaf(a.x, m[u], acc.x);
                acc.y = fmaf(a.y, m[u], acc.y);
                acc.z = fmaf(a.z, m[u], acc.z);
                acc.w = fmaf(a.w, m[u], acc.w);
            }
        }
    }
#pragma unroll
    for (int mk = QF; mk < 64; mk <<= 1) {
        acc.x += __shfl_xor(acc.x, mk);
        acc.y += __shfl_xor(acc.y, mk);
        acc.z += __shfl_xor(acc.z, mk);
        acc.w += __shfl_xor(acc.w, mk);
    }
    int f = lane;
    float s = 0.f;
#pragma unroll
    for (int q2 = 0; q2 < QF; ++q2) {
        float bx = __shfl(acc.x, q2);
        float by = __shfl(acc.y, q2);
        float bz = __shfl(acc.z, q2);
        float bw = __shfl(acc.w, q2);
        s = fmaf(bx, w1[(4 * q2 + 0) * 64 + f], s);
        s = fmaf(by, w1[(4 * q2 + 1) * 64 + f], s);
        s = fmaf(bz, w1[(4 * q2 + 2) * 64 + f], s);
        s = fmaf(bw, w1[(4 * q2 + 3) * 64 + f], s);
    }
    float dv = dis[wid];
    float h = fmaxf(fmaf(dv, s, b1[f]), 0.f) * dv;
    hOut[(size_t)wid * 64 + f] = h;
}

__global__ void k_agg64(const int* __restrict__ rowPtr, const int* __restrict__ srcIdx,
                        const float* __restrict__ y, const float* __restrict__ dis,
                        float* __restrict__ z, int N) {
    constexpr int QF = 16, RPI = 4, U = 8, CH = RPI * U;
    int wid = (blockIdx.x * blockDim.x + threadIdx.x) >> 6;
    if (wid >= N) return;
    int lane = threadIdx.x & 63;
    int q = lane & (QF - 1);
    int r = lane / QF;
    int beg = rowPtr[wid], end = rowPtr[wid + 1];
    const float4* yq = (const float4*)y;
    float4 acc = {0.f, 0.f, 0.f, 0.f};
    if (r == 0) acc = yq[(size_t)wid * QF + q];
    if (end > beg) {
        int last = end - 1;
        for (int base = beg; base < end; base += CH) {
            int s[U];
            float m[U];
#pragma unroll
            for (int u = 0; u < U; ++u) {
                int i = base + r + u * RPI;
                m[u] = (i < end) ? 1.f : 0.f;
                s[u] = __builtin_nontemporal_load(srcIdx + min(i, last));
            }
#pragma unroll
            for (int u = 0; u < U; ++u) {
                float4 a = yq[(size_t)s[u] * QF + q];
                acc.x = fmaf(a.x, m[u], acc.x);
                acc.y = fmaf(a.y, m[u], acc.y);
                acc.z = fmaf(a.z, m[u], acc.z);
                acc.w = fmaf(a.w, m[u], acc.w);
            }
        }
    }
#pragma unroll
    for (int mk = QF; mk < 64; mk <<= 1) {
        acc.x += __shfl_xor(acc.x, mk);
        acc.y += __shfl_xor(acc.y, mk);
        acc.z += __shfl_xor(acc.z, mk);
        acc.w += __shfl_xor(acc.w, mk);
    }
    if (r == 0) {
        float dv = dis[wid];
        vfloat4 o = {acc.x * dv, acc.y * dv, acc.z * dv, acc.w * dv};
        __builtin_nontemporal_store(o, (vfloat4*)z + (size_t)wid * QF + q);
    }
}

__global__ void k_poolhead(const float* __restrict__ z2, const float* __restrict__ w2,
                           const float* __restrict__ b2, const int* __restrict__ batch,
                           const float* __restrict__ wf1, const float* __restrict__ bf1,
                           const float* __restrict__ wf2, const float* __restrict__ bf2,
                           float* __restrict__ out, int N) {
    __shared__ float w2s[64 * 64];
    __shared__ float red[8][64];
    __shared__ float pooled[64];
    __shared__ float gv[32];
    __shared__ int range[2];
    int g = blockIdx.x;
    int t = threadIdx.x;  // 512
    for (int i = t; i < 4096; i += 512) w2s[i] = w2[i];
    if (t < 2) {
        int target = g + t;
        int lo = 0, hi = N;
        while (lo < hi) {
            int mid = (lo + hi) >> 1;
            if (batch[mid] < target) lo = mid + 1; else hi = mid;
        }
        range[t] = lo;
    }
    __syncthreads();
    int s = range[0], e = range[1];
    int w = t >> 6, f = t & 63;
    float bf = b2[f];
    float acc = 0.f;
    for (int n = s + w; n < e; n += 8) {
        const vfloat4* zr = (const vfloat4*)(z2 + (size_t)n * 64);
        float h = bf;
#pragma unroll
        for (int kq = 0; kq < 16; ++kq) {
            vfloat4 zv = __builtin_nontemporal_load(zr + kq);
            h += zv[0] * w2s[(4 * kq + 0) * 64 + f];
            h += zv[1] * w2s[(4 * kq + 1) * 64 + f];
            h += zv[2] * w2s[(4 * kq + 2) * 64 + f];
            h += zv[3] * w2s[(4 * kq + 3) * 64 + f];
        }
        acc += fmaxf(h, 0.f);
    }
    red[w][f] = acc;
    __syncthreads();
    if (t < 64) {
        float c = (float)(e - s);
        c = c > 1.f ? c : 1.f;
        float sum = 0.f;
#pragma unroll
        for (int j = 0; j < 8; ++j) sum += red[j][t];
        pooled[t] = sum / c;
    }
    __syncthreads();
    if (t < 32) {
        float sv = bf1[t];
#pragma unroll
        for (int k = 0; k < 64; ++k) sv += pooled[k] * wf1[k * 32 + t];
        gv[t] = fmaxf(sv, 0.f);
    }
    __syncthreads();
    if (t == 0) {
        float sv = bf2[0];
#pragma unroll
        for (int j = 0; j < 32; ++j) sv += gv[j] * wf2[j];
        out[g] = sv;
    }
}

extern "C" void kernel_launch(void* const* d_in, const int* in_sizes, int n_in,
                              void* d_out, int out_size, void* d_ws, size_t ws_size,
                              hipStream_t stream) {
    const float* x      = (const float*)d_in[0];
    const int*   ei     = (const int*)d_in[2];
    const int*   batch  = (const int*)d_in[3];
    const float* w_node = (const float*)d_in[4];
    const float* b_node = (const float*)d_in[5];
    const float* w1  = (const float*)d_in[8];
    const float* b1  = (const float*)d_in[9];
    const float* w2  = (const float*)d_in[10];
    const float* b2  = (const float*)d_in[11];
    const float* wf1 = (const float*)d_in[12];
    const float* bf1 = (const float*)d_in[13];
    const float* wf2 = (const float*)d_in[14];
    const float* bf2 = (const float*)d_in[15];
    float* out = (float*)d_out;

    const int N = in_sizes[0] / 2;  // 100000
    const int E = in_sizes[2] / 2;  // 3200000
    const int G = out_size;         // 1024
    const int NB = (N + 255) >> 8;  // 391

    auto align256 = [](size_t v) { return (v + 255) & ~(size_t)255; };
    char* ws = (char*)d_ws;
    size_t off = 0;
    float* dis     = (float*)(ws + off); off += align256((size_t)N * 4);
    int*   rowPtr  = (int*)(ws + off);   off += align256((size_t)(N + 1) * 4);
    int*   bcur    = (int*)(ws + off);   off += align256((size_t)NBMAX * 4);
    int*   srcIdx  = (int*)(ws + off);   off += align256((size_t)E * 4);
    float* region1 = (float*)(ws + off); off += align256((size_t)N * 64 * 4);  // pairBuf, then z2
    float* hT1     = (float*)(ws + off); off += align256((size_t)N * 64 * 4);  // h~1 [N,64]
    float* hT0     = (float*)(ws + off); off += align256((size_t)N * 32 * 4);  // h~0 [N,32] dedicated

    unsigned int* pairBuf = (unsigned int*)region1;  // 19.2 MB < 25.6 MB
    float* z2 = region1;                             // [N,64] (pairBuf dead by layer 2)

    const int B = 256;

    k_initcur<<<1, NBMAX, 0, stream>>>(bcur);
    {
        int nblk = (E + B * 32 - 1) / (B * 32);  // 391
        k_passA<<<nblk, B, 0, stream>>>(ei, bcur, pairBuf, E);
    }
    k_passB<<<NB, B, 0, stream>>>(bcur, pairBuf, rowPtr, dis, srcIdx,
                                  x, w_node, b_node, hT0, N, E);

    k_agg32mm<<<(N * 64 + B - 1) / B, B, 0, stream>>>(rowPtr, srcIdx, hT0, dis,
                                                      w1, b1, hT1, N);

    k_agg64<<<(N * 64 + B - 1) / B, B, 0, stream>>>(rowPtr, srcIdx, hT1, dis, z2, N);

    k_poolhead<<<G, 512, 0, stream>>>(z2, w2, b2, batch, wf1, bf1, wf2, bf2, out, N);
}

// Round 9
// 324.197 us; speedup vs baseline: 1.4678x; 1.4678x over previous
//
#include <hip/hip_runtime.h>

// ---------------------------------------------------------------------------
// GNN_20237885899323: 2-layer GCN + mean-pool + MLP head, all fp32.
// Round 9: revert round-8's NT stores on SCATTERED writes (pairBuf in passA,
// srcIdx in passB) — NT bypassed L2 write-merging, 10x write amplification
// (WRITE_SIZE 12.8->125 MB, passA 35->120us). Keep: NT loads on sequential
// streams, NT store of z2 (full-line coalesced), fused passB, 512-thr poolhead.
// ---------------------------------------------------------------------------

typedef float vfloat4 __attribute__((ext_vector_type(4)));

#define NBMAX 512
#define BCAP 12288
#define CAPL 10240

__global__ void k_initcur(int* __restrict__ bcur) {
    bcur[threadIdx.x] = threadIdx.x * BCAP;  // 512 threads
}

__global__ void k_passA(const int* __restrict__ ei, int* __restrict__ bcur,
                        unsigned int* __restrict__ pairBuf, int E) {
    __shared__ int h[NBMAX];
    __shared__ int base[NBMAX];
    const int T = 256, EPT = 32;
    int chunk = blockIdx.x * (T * EPT);
    int t = threadIdx.x;
    h[t] = 0; h[t + 256] = 0;
    __syncthreads();
    int nE = min(E - chunk, T * EPT);
    for (int i = t; i < nE; i += T)
        atomicAdd(&h[ei[E + chunk + i] >> 8], 1);
    __syncthreads();
    for (int bb = t; bb < NBMAX; bb += T) {
        int c = h[bb];
        base[bb] = c > 0 ? atomicAdd(&bcur[bb], c) : 0;
        h[bb] = 0;
    }
    __syncthreads();
    for (int i = t; i < nE; i += T) {
        int s = ei[chunk + i];
        int d = ei[E + chunk + i];
        int bb = d >> 8;
        int pos = base[bb] + atomicAdd(&h[bb], 1);
        pairBuf[pos] = ((unsigned int)(d & 255) << 24) | (unsigned int)s;  // cached store: L2 merges bursts
    }
}

__global__ void k_passB(const int* __restrict__ bcur,
                        const unsigned int* __restrict__ pairBuf,
                        int* __restrict__ rowPtr, float* __restrict__ dis,
                        int* __restrict__ srcIdx, const float* __restrict__ x,
                        const float* __restrict__ wn, const float* __restrict__ bn,
                        float* __restrict__ h0, int N, int E) {
    __shared__ unsigned int eLds[CAPL];
    __shared__ int hist[256];
    __shared__ int scan[256];
    __shared__ float disL[256];
    __shared__ float wsh[64];
    __shared__ float bsh[32];
    int b = blockIdx.x;
    int t = threadIdx.x;  // 256
    int count = bcur[b] - b * BCAP;
    const unsigned int* src = pairBuf + (size_t)b * BCAP;
    int part = 0;
    for (int i = t; i < b; i += 256) part += bcur[i] - i * BCAP;
    scan[t] = part;
    __syncthreads();
    for (int o = 128; o > 0; o >>= 1) {
        if (t < o) scan[t] += scan[t + o];
        __syncthreads();
    }
    int gbase = scan[0];
    __syncthreads();
    hist[t] = 0;
    if (t < 64) wsh[t] = wn[t];
    if (t < 32) bsh[t] = bn[t];
    int nStage = min(count, CAPL);
    for (int i = t; i < nStage; i += 256) eLds[i] = __builtin_nontemporal_load(src + i);
    __syncthreads();
    for (int i = t; i < nStage; i += 256) atomicAdd(&hist[eLds[i] >> 24], 1);
    for (int i = CAPL + t; i < count; i += 256)
        atomicAdd(&hist[__builtin_nontemporal_load(src + i) >> 24], 1);
    __syncthreads();
    int c = hist[t];
    scan[t] = c;
    __syncthreads();
    for (int o = 1; o < 256; o <<= 1) {
        int v = (t >= o) ? scan[t - o] : 0;
        __syncthreads();
        scan[t] += v;
        __syncthreads();
    }
    int excl = scan[t] - c;
    int node = (b << 8) + t;
    float dval = rsqrtf((float)c + 1.0f);
    disL[t] = dval;
    if (node < N) {
        rowPtr[node] = gbase + excl;
        dis[node] = dval;
        if (node == N - 1) rowPtr[N] = E;
    }
    hist[t] = excl;
    __syncthreads();
    for (int i = t; i < nStage; i += 256) {
        unsigned int e = eLds[i];
        int pos = atomicAdd(&hist[e >> 24], 1);
        srcIdx[gbase + pos] = (int)(e & 0xFFFFFFu);  // cached store: clustered, L2 merges
    }
    for (int i = CAPL + t; i < count; i += 256) {
        unsigned int e = __builtin_nontemporal_load(src + i);
        int pos = atomicAdd(&hist[e >> 24], 1);
        srcIdx[gbase + pos] = (int)(e & 0xFFFFFFu);
    }
    __syncthreads();
    for (int ch = 0; ch < 32; ++ch) {
        int ln = ch * 8 + (t >> 5);
        int f = t & 31;
        int n2 = (b << 8) + ln;
        if (n2 < N) {
            float v = x[2 * n2] * wsh[f] + x[2 * n2 + 1] * wsh[32 + f] + bsh[f];
            v = fmaxf(v, 0.f);
            h0[(size_t)n2 * 32 + f] = v * disL[ln];
        }
    }
}

__global__ void k_agg32mm(const int* __restrict__ rowPtr, const int* __restrict__ srcIdx,
                          const float* __restrict__ y, const float* __restrict__ dis,
                          const float* __restrict__ w1, const float* __restrict__ b1,
                          float* __restrict__ hOut, int N) {
    constexpr int QF = 8, RPI = 8, U = 4, CH = RPI * U;
    int wid = (blockIdx.x * blockDim.x + threadIdx.x) >> 6;
    if (wid >= N) return;
    int lane = threadIdx.x & 63;
    int q = lane & (QF - 1);
    int r = lane / QF;
    int beg = rowPtr[wid], end = rowPtr[wid + 1];
    const float4* yq = (const float4*)y;
    float4 acc = {0.f, 0.f, 0.f, 0.f};
    if (r == 0) acc = yq[(size_t)wid * QF + q];
    if (end > beg) {
        int last = end - 1;
        for (int base = beg; base < end; base += CH) {
            int s[U];
            float m[U];
#pragma unroll
            for (int u = 0; u < U; ++u) {
                int i = base + r + u * RPI;
                m[u] = (i < end) ? 1.f : 0.f;
                s[u] = __builtin_nontemporal_load(srcIdx + min(i, last));
            }
#pragma unroll
            for (int u = 0; u < U; ++u) {
                float4 a = yq[(size_t)s[u] * QF + q];
                acc.x = fmaf(a.x, m[u], acc.x);
                acc.y = fmaf(a.y, m[u], acc.y);
                acc.z = fmaf(a.z, m[u], acc.z);
                acc.w = fmaf(a.w, m[u], acc.w);
            }
        }
    }
#pragma unroll
    for (int mk = QF; mk < 64; mk <<= 1) {
        acc.x += __shfl_xor(acc.x, mk);
        acc.y += __shfl_xor(acc.y, mk);
        acc.z += __shfl_xor(acc.z, mk);
        acc.w += __shfl_xor(acc.w, mk);
    }
    int f = lane;
    float s = 0.f;
#pragma unroll
    for (int q2 = 0; q2 < QF; ++q2) {
        float bx = __shfl(acc.x, q2);
        float by = __shfl(acc.y, q2);
        float bz = __shfl(acc.z, q2);
        float bw = __shfl(acc.w, q2);
        s = fmaf(bx, w1[(4 * q2 + 0) * 64 + f], s);
        s = fmaf(by, w1[(4 * q2 + 1) * 64 + f], s);
        s = fmaf(bz, w1[(4 * q2 + 2) * 64 + f], s);
        s = fmaf(bw, w1[(4 * q2 + 3) * 64 + f], s);
    }
    float dv = dis[wid];
    float h = fmaxf(fmaf(dv, s, b1[f]), 0.f) * dv;
    hOut[(size_t)wid * 64 + f] = h;
}

__global__ void k_agg64(const int* __restrict__ rowPtr, const int* __restrict__ srcIdx,
                        const float* __restrict__ y, const float* __restrict__ dis,
                        float* __restrict__ z, int N) {
    constexpr int QF = 16, RPI = 4, U = 8, CH = RPI * U;
    int wid = (blockIdx.x * blockDim.x + threadIdx.x) >> 6;
    if (wid >= N) return;
    int lane = threadIdx.x & 63;
    int q = lane & (QF - 1);
    int r = lane / QF;
    int beg = rowPtr[wid], end = rowPtr[wid + 1];
    const float4* yq = (const float4*)y;
    float4 acc = {0.f, 0.f, 0.f, 0.f};
    if (r == 0) acc = yq[(size_t)wid * QF + q];
    if (end > beg) {
        int last = end - 1;
        for (int base = beg; base < end; base += CH) {
            int s[U];
            float m[U];
#pragma unroll
            for (int u = 0; u < U; ++u) {
                int i = base + r + u * RPI;
                m[u] = (i < end) ? 1.f : 0.f;
                s[u] = __builtin_nontemporal_load(srcIdx + min(i, last));
            }
#pragma unroll
            for (int u = 0; u < U; ++u) {
                float4 a = yq[(size_t)s[u] * QF + q];
                acc.x = fmaf(a.x, m[u], acc.x);
                acc.y = fmaf(a.y, m[u], acc.y);
                acc.z = fmaf(a.z, m[u], acc.z);
                acc.w = fmaf(a.w, m[u], acc.w);
            }
        }
    }
#pragma unroll
    for (int mk = QF; mk < 64; mk <<= 1) {
        acc.x += __shfl_xor(acc.x, mk);
        acc.y += __shfl_xor(acc.y, mk);
        acc.z += __shfl_xor(acc.z, mk);
        acc.w += __shfl_xor(acc.w, mk);
    }
    if (r == 0) {
        float dv = dis[wid];
        vfloat4 o = {acc.x * dv, acc.y * dv, acc.z * dv, acc.w * dv};
        __builtin_nontemporal_store(o, (vfloat4*)z + (size_t)wid * QF + q);  // full-line coalesced
    }
}

__global__ void k_poolhead(const float* __restrict__ z2, const float* __restrict__ w2,
                           const float* __restrict__ b2, const int* __restrict__ batch,
                           const float* __restrict__ wf1, const float* __restrict__ bf1,
                           const float* __restrict__ wf2, const float* __restrict__ bf2,
                           float* __restrict__ out, int N) {
    __shared__ float w2s[64 * 64];
    __shared__ float red[8][64];
    __shared__ float pooled[64];
    __shared__ float gv[32];
    __shared__ int range[2];
    int g = blockIdx.x;
    int t = threadIdx.x;  // 512
    for (int i = t; i < 4096; i += 512) w2s[i] = w2[i];
    if (t < 2) {
        int target = g + t;
        int lo = 0, hi = N;
        while (lo < hi) {
            int mid = (lo + hi) >> 1;
            if (batch[mid] < target) lo = mid + 1; else hi = mid;
        }
        range[t] = lo;
    }
    __syncthreads();
    int s = range[0], e = range[1];
    int w = t >> 6, f = t & 63;
    float bf = b2[f];
    float acc = 0.f;
    for (int n = s + w; n < e; n += 8) {
        const vfloat4* zr = (const vfloat4*)(z2 + (size_t)n * 64);
        float h = bf;
#pragma unroll
        for (int kq = 0; kq < 16; ++kq) {
            vfloat4 zv = __builtin_nontemporal_load(zr + kq);
            h += zv[0] * w2s[(4 * kq + 0) * 64 + f];
            h += zv[1] * w2s[(4 * kq + 1) * 64 + f];
            h += zv[2] * w2s[(4 * kq + 2) * 64 + f];
            h += zv[3] * w2s[(4 * kq + 3) * 64 + f];
        }
        acc += fmaxf(h, 0.f);
    }
    red[w][f] = acc;
    __syncthreads();
    if (t < 64) {
        float c = (float)(e - s);
        c = c > 1.f ? c : 1.f;
        float sum = 0.f;
#pragma unroll
        for (int j = 0; j < 8; ++j) sum += red[j][t];
        pooled[t] = sum / c;
    }
    __syncthreads();
    if (t < 32) {
        float sv = bf1[t];
#pragma unroll
        for (int k = 0; k < 64; ++k) sv += pooled[k] * wf1[k * 32 + t];
        gv[t] = fmaxf(sv, 0.f);
    }
    __syncthreads();
    if (t == 0) {
        float sv = bf2[0];
#pragma unroll
        for (int j = 0; j < 32; ++j) sv += gv[j] * wf2[j];
        out[g] = sv;
    }
}

extern "C" void kernel_launch(void* const* d_in, const int* in_sizes, int n_in,
                              void* d_out, int out_size, void* d_ws, size_t ws_size,
                              hipStream_t stream) {
    const float* x      = (const float*)d_in[0];
    const int*   ei     = (const int*)d_in[2];
    const int*   batch  = (const int*)d_in[3];
    const float* w_node = (const float*)d_in[4];
    const float* b_node = (const float*)d_in[5];
    const float* w1  = (const float*)d_in[8];
    const float* b1  = (const float*)d_in[9];
    const float* w2  = (const float*)d_in[10];
    const float* b2  = (const float*)d_in[11];
    const float* wf1 = (const float*)d_in[12];
    const float* bf1 = (const float*)d_in[13];
    const float* wf2 = (const float*)d_in[14];
    const float* bf2 = (const float*)d_in[15];
    float* out = (float*)d_out;

    const int N = in_sizes[0] / 2;  // 100000
    const int E = in_sizes[2] / 2;  // 3200000
    const int G = out_size;         // 1024
    const int NB = (N + 255) >> 8;  // 391

    auto align256 = [](size_t v) { return (v + 255) & ~(size_t)255; };
    char* ws = (char*)d_ws;
    size_t off = 0;
    float* dis     = (float*)(ws + off); off += align256((size_t)N * 4);
    int*   rowPtr  = (int*)(ws + off);   off += align256((size_t)(N + 1) * 4);
    int*   bcur    = (int*)(ws + off);   off += align256((size_t)NBMAX * 4);
    int*   srcIdx  = (int*)(ws + off);   off += align256((size_t)E * 4);
    float* region1 = (float*)(ws + off); off += align256((size_t)N * 64 * 4);  // pairBuf, then z2
    float* hT1     = (float*)(ws + off); off += align256((size_t)N * 64 * 4);  // h~1 [N,64]
    float* hT0     = (float*)(ws + off); off += align256((size_t)N * 32 * 4);  // h~0 [N,32] dedicated

    unsigned int* pairBuf = (unsigned int*)region1;  // 19.2 MB < 25.6 MB
    float* z2 = region1;                             // [N,64] (pairBuf dead by layer 2)

    const int B = 256;

    k_initcur<<<1, NBMAX, 0, stream>>>(bcur);
    {
        int nblk = (E + B * 32 - 1) / (B * 32);  // 391
        k_passA<<<nblk, B, 0, stream>>>(ei, bcur, pairBuf, E);
    }
    k_passB<<<NB, B, 0, stream>>>(bcur, pairBuf, rowPtr, dis, srcIdx,
                                  x, w_node, b_node, hT0, N, E);

    k_agg32mm<<<(N * 64 + B - 1) / B, B, 0, stream>>>(rowPtr, srcIdx, hT0, dis,
                                                      w1, b1, hT1, N);

    k_agg64<<<(N * 64 + B - 1) / B, B, 0, stream>>>(rowPtr, srcIdx, hT1, dis, z2, N);

    k_poolhead<<<G, 512, 0, stream>>>(z2, w2, b2, batch, wf1, bf1, wf2, bf2, out, N);
}

// Round 10
// 307.556 us; speedup vs baseline: 1.5472x; 1.0541x over previous
//
#include <hip/hip_runtime.h>

// ---------------------------------------------------------------------------
// GNN_20237885899323: 2-layer GCN + mean-pool + MLP head, all fp32.
// Round 10: layer-1 gather works on a rank-2-derived array: h~0[n] is a
// function of (x0,x1,dis) only. Gather packed p[n]={x0,x1,dis,0} (1.6 MB --
// fits ONE XCD's 4MB L2) and recompute the 32 features in-register per edge
// (~18 VALU ops/lane). Layer-1 leaves the ~3.8 TB/s random-line service bound
// entirely. Also reverts r8/r9 losses: plain z2 store (L2-resident for
// poolhead), r7 256-thr poolhead with wcol in VGPRs. passB keeps the fused
// scan but its epilogue is now the 16B/node p-build (was 128B/node h0).
// ---------------------------------------------------------------------------

typedef float vfloat4 __attribute__((ext_vector_type(4)));

#define NBMAX 512
#define BCAP 12288
#define CAPL 10240

__global__ void k_initcur(int* __restrict__ bcur) {
    bcur[threadIdx.x] = threadIdx.x * BCAP;  // 512 threads
}

__global__ void k_passA(const int* __restrict__ ei, int* __restrict__ bcur,
                        unsigned int* __restrict__ pairBuf, int E) {
    __shared__ int h[NBMAX];
    __shared__ int base[NBMAX];
    const int T = 256, EPT = 32;
    int chunk = blockIdx.x * (T * EPT);
    int t = threadIdx.x;
    h[t] = 0; h[t + 256] = 0;
    __syncthreads();
    int nE = min(E - chunk, T * EPT);
    for (int i = t; i < nE; i += T)
        atomicAdd(&h[ei[E + chunk + i] >> 8], 1);
    __syncthreads();
    for (int bb = t; bb < NBMAX; bb += T) {
        int c = h[bb];
        base[bb] = c > 0 ? atomicAdd(&bcur[bb], c) : 0;
        h[bb] = 0;
    }
    __syncthreads();
    for (int i = t; i < nE; i += T) {
        int s = ei[chunk + i];
        int d = ei[E + chunk + i];
        int bb = d >> 8;
        int pos = base[bb] + atomicAdd(&h[bb], 1);
        pairBuf[pos] = ((unsigned int)(d & 255) << 24) | (unsigned int)s;  // cached: L2 merges bursts
    }
}

// pass B: per-bucket counting sort -> rowPtr, dis, srcIdx, p={x0,x1,dis,0}
__global__ void k_passB(const int* __restrict__ bcur,
                        const unsigned int* __restrict__ pairBuf,
                        int* __restrict__ rowPtr, float* __restrict__ dis,
                        int* __restrict__ srcIdx, const float* __restrict__ x,
                        float4* __restrict__ p, int N, int E) {
    __shared__ unsigned int eLds[CAPL];
    __shared__ int hist[256];
    __shared__ int scan[256];
    int b = blockIdx.x;
    int t = threadIdx.x;  // 256
    int count = bcur[b] - b * BCAP;
    const unsigned int* src = pairBuf + (size_t)b * BCAP;
    // gbase = sum of bucket counts below b (redundant per-block reduce)
    int part = 0;
    for (int i = t; i < b; i += 256) part += bcur[i] - i * BCAP;
    scan[t] = part;
    __syncthreads();
    for (int o = 128; o > 0; o >>= 1) {
        if (t < o) scan[t] += scan[t + o];
        __syncthreads();
    }
    int gbase = scan[0];
    __syncthreads();
    hist[t] = 0;
    int nStage = min(count, CAPL);
    for (int i = t; i < nStage; i += 256) eLds[i] = __builtin_nontemporal_load(src + i);
    __syncthreads();
    for (int i = t; i < nStage; i += 256) atomicAdd(&hist[eLds[i] >> 24], 1);
    for (int i = CAPL + t; i < count; i += 256)
        atomicAdd(&hist[__builtin_nontemporal_load(src + i) >> 24], 1);
    __syncthreads();
    int c = hist[t];
    scan[t] = c;
    __syncthreads();
    for (int o = 1; o < 256; o <<= 1) {
        int v = (t >= o) ? scan[t - o] : 0;
        __syncthreads();
        scan[t] += v;
        __syncthreads();
    }
    int excl = scan[t] - c;
    int node = (b << 8) + t;
    float dval = rsqrtf((float)c + 1.0f);  // +1 self loop
    if (node < N) {
        rowPtr[node] = gbase + excl;
        dis[node] = dval;
        float4 pv;
        pv.x = x[2 * node]; pv.y = x[2 * node + 1]; pv.z = dval; pv.w = 0.f;
        p[node] = pv;
        if (node == N - 1) rowPtr[N] = E;
    }
    hist[t] = excl;
    __syncthreads();
    for (int i = t; i < nStage; i += 256) {
        unsigned int e = eLds[i];
        int pos = atomicAdd(&hist[e >> 24], 1);
        srcIdx[gbase + pos] = (int)(e & 0xFFFFFFu);  // cached: clustered, L2 merges
    }
    for (int i = CAPL + t; i < count; i += 256) {
        unsigned int e = __builtin_nontemporal_load(src + i);
        int pos = atomicAdd(&hist[e >> 24], 1);
        srcIdx[gbase + pos] = (int)(e & 0xFFFFFFu);
    }
}

// layer 1: gather p[src] (16B, 1.6MB working set = L2-resident), recompute
// h~0 features in-register, accumulate; butterfly reduce; fused @w1 epilogue.
// h~1[v][f] = dis*relu(dis*(agg@w1)+b1), agg = h~0[v] + sum_src h~0[src].
__global__ void k_agg32x(const int* __restrict__ rowPtr, const int* __restrict__ srcIdx,
                         const float4* __restrict__ p, const float* __restrict__ wn,
                         const float* __restrict__ bn, const float* __restrict__ w1,
                         const float* __restrict__ b1, float* __restrict__ hOut, int N) {
    constexpr int RPI = 8, U = 4, CH = RPI * U;  // 8 row groups, 4 deep
    int wid = (blockIdx.x * blockDim.x + threadIdx.x) >> 6;
    if (wid >= N) return;
    int lane = threadIdx.x & 63;
    int q = lane & 7;   // feature quad: f = 4q..4q+3
    int r = lane >> 3;  // row group 0..7
    float wn0[4], wn1[4], bnv[4];
#pragma unroll
    for (int j = 0; j < 4; ++j) {
        wn0[j] = wn[4 * q + j];
        wn1[j] = wn[32 + 4 * q + j];
        bnv[j] = bn[4 * q + j];
    }
    float4 pd = p[wid];
    float accv[4] = {0.f, 0.f, 0.f, 0.f};
    if (r == 0) {  // self loop: h~0[wid]
#pragma unroll
        for (int j = 0; j < 4; ++j) {
            float v = fmaf(pd.x, wn0[j], fmaf(pd.y, wn1[j], bnv[j]));
            accv[j] = fmaxf(v, 0.f) * pd.z;
        }
    }
    int beg = rowPtr[wid], end = rowPtr[wid + 1];
    if (end > beg) {
        int last = end - 1;
        for (int base = beg; base < end; base += CH) {
            int s[U];
            float m[U];
#pragma unroll
            for (int u = 0; u < U; ++u) {
                int i = base + r + u * RPI;
                m[u] = (i < end) ? 1.f : 0.f;
                s[u] = __builtin_nontemporal_load(srcIdx + min(i, last));
            }
            float4 ps[U];
#pragma unroll
            for (int u = 0; u < U; ++u) ps[u] = p[s[u]];
#pragma unroll
            for (int u = 0; u < U; ++u) {
                float scale = ps[u].z * m[u];
#pragma unroll
                for (int j = 0; j < 4; ++j) {
                    float v = fmaf(ps[u].x, wn0[j], fmaf(ps[u].y, wn1[j], bnv[j]));
                    accv[j] = fmaf(fmaxf(v, 0.f), scale, accv[j]);
                }
            }
        }
    }
#pragma unroll
    for (int mk = 8; mk < 64; mk <<= 1) {
#pragma unroll
        for (int j = 0; j < 4; ++j) accv[j] += __shfl_xor(accv[j], mk);
    }
    // lanes with q=q2 (e.g. lane q2) hold the reduced quad for features 4q2..4q2+3
    int f = lane;
    float s = 0.f;
#pragma unroll
    for (int q2 = 0; q2 < 8; ++q2) {
#pragma unroll
        for (int j = 0; j < 4; ++j) {
            float bv = __shfl(accv[j], q2);
            s = fmaf(bv, w1[(4 * q2 + j) * 64 + f], s);
        }
    }
    float dv = pd.z;
    float h = fmaxf(fmaf(dv, s, b1[f]), 0.f) * dv;
    hOut[(size_t)wid * 64 + f] = h;
}

// layer 2 aggregation: one wave per dst node, rows of 64 floats (the pinned
// ~3.8 TB/s random-line service bound). Plain z2 store (L2-resident for pool).
__global__ void k_agg64(const int* __restrict__ rowPtr, const int* __restrict__ srcIdx,
                        const float* __restrict__ y, const float* __restrict__ dis,
                        float* __restrict__ z, int N) {
    constexpr int QF = 16, RPI = 4, U = 8, CH = RPI * U;
    int wid = (blockIdx.x * blockDim.x + threadIdx.x) >> 6;
    if (wid >= N) return;
    int lane = threadIdx.x & 63;
    int q = lane & (QF - 1);
    int r = lane / QF;
    int beg = rowPtr[wid], end = rowPtr[wid + 1];
    const float4* yq = (const float4*)y;
    float4 acc = {0.f, 0.f, 0.f, 0.f};
    if (r == 0) acc = yq[(size_t)wid * QF + q];
    if (end > beg) {
        int last = end - 1;
        for (int base = beg; base < end; base += CH) {
            int s[U];
            float m[U];
#pragma unroll
            for (int u = 0; u < U; ++u) {
                int i = base + r + u * RPI;
                m[u] = (i < end) ? 1.f : 0.f;
                s[u] = __builtin_nontemporal_load(srcIdx + min(i, last));
            }
#pragma unroll
            for (int u = 0; u < U; ++u) {
                float4 a = yq[(size_t)s[u] * QF + q];
                acc.x = fmaf(a.x, m[u], acc.x);
                acc.y = fmaf(a.y, m[u], acc.y);
                acc.z = fmaf(a.z, m[u], acc.z);
                acc.w = fmaf(a.w, m[u], acc.w);
            }
        }
    }
#pragma unroll
    for (int mk = QF; mk < 64; mk <<= 1) {
        acc.x += __shfl_xor(acc.x, mk);
        acc.y += __shfl_xor(acc.y, mk);
        acc.z += __shfl_xor(acc.z, mk);
        acc.w += __shfl_xor(acc.w, mk);
    }
    if (r == 0) {
        float dv = dis[wid];
        float4 o = {acc.x * dv, acc.y * dv, acc.z * dv, acc.w * dv};
        ((float4*)z)[(size_t)wid * QF + q] = o;  // plain store: stays in L2 for poolhead
    }
}

// block-per-graph (256 thr, r7 version): binary-search node range in sorted
// batch; h2 = relu(z2@w2+b2) on the fly (w2 column in VGPRs); mean; MLP head.
__global__ void k_poolhead(const float* __restrict__ z2, const float* __restrict__ w2,
                           const float* __restrict__ b2, const int* __restrict__ batch,
                           const float* __restrict__ wf1, const float* __restrict__ bf1,
                           const float* __restrict__ wf2, const float* __restrict__ bf2,
                           float* __restrict__ out, int N) {
    __shared__ float red[4][64];
    __shared__ float pooled[64];
    __shared__ float gv[32];
    __shared__ int range[2];
    int g = blockIdx.x;
    int t = threadIdx.x;  // 256
    if (t < 2) {
        int target = g + t;
        int lo = 0, hi = N;
        while (lo < hi) {
            int mid = (lo + hi) >> 1;
            if (batch[mid] < target) lo = mid + 1; else hi = mid;
        }
        range[t] = lo;
    }
    __syncthreads();
    int s = range[0], e = range[1];
    int w = t >> 6, f = t & 63;
    float wcol[64];
#pragma unroll
    for (int k = 0; k < 64; ++k) wcol[k] = w2[k * 64 + f];
    float bf = b2[f];
    float acc = 0.f;
    for (int n = s + w; n < e; n += 4) {
        const float4* zr = (const float4*)(z2 + (size_t)n * 64);
        float h = bf;
#pragma unroll
        for (int kq = 0; kq < 16; ++kq) {
            float4 zv = zr[kq];
            h += zv.x * wcol[4 * kq + 0];
            h += zv.y * wcol[4 * kq + 1];
            h += zv.z * wcol[4 * kq + 2];
            h += zv.w * wcol[4 * kq + 3];
        }
        acc += fmaxf(h, 0.f);
    }
    red[w][f] = acc;
    __syncthreads();
    if (t < 64) {
        float c = (float)(e - s);
        c = c > 1.f ? c : 1.f;
        pooled[t] = (red[0][t] + red[1][t] + red[2][t] + red[3][t]) / c;
    }
    __syncthreads();
    if (t < 32) {
        float sv = bf1[t];
#pragma unroll
        for (int k = 0; k < 64; ++k) sv += pooled[k] * wf1[k * 32 + t];
        gv[t] = fmaxf(sv, 0.f);
    }
    __syncthreads();
    if (t == 0) {
        float sv = bf2[0];
#pragma unroll
        for (int j = 0; j < 32; ++j) sv += gv[j] * wf2[j];
        out[g] = sv;
    }
}

extern "C" void kernel_launch(void* const* d_in, const int* in_sizes, int n_in,
                              void* d_out, int out_size, void* d_ws, size_t ws_size,
                              hipStream_t stream) {
    const float* x      = (const float*)d_in[0];
    const int*   ei     = (const int*)d_in[2];
    const int*   batch  = (const int*)d_in[3];
    const float* w_node = (const float*)d_in[4];
    const float* b_node = (const float*)d_in[5];
    const float* w1  = (const float*)d_in[8];
    const float* b1  = (const float*)d_in[9];
    const float* w2  = (const float*)d_in[10];
    const float* b2  = (const float*)d_in[11];
    const float* wf1 = (const float*)d_in[12];
    const float* bf1 = (const float*)d_in[13];
    const float* wf2 = (const float*)d_in[14];
    const float* bf2 = (const float*)d_in[15];
    float* out = (float*)d_out;

    const int N = in_sizes[0] / 2;  // 100000
    const int E = in_sizes[2] / 2;  // 3200000
    const int G = out_size;         // 1024
    const int NB = (N + 255) >> 8;  // 391

    auto align256 = [](size_t v) { return (v + 255) & ~(size_t)255; };
    char* ws = (char*)d_ws;
    size_t off = 0;
    float*  dis     = (float*)(ws + off);  off += align256((size_t)N * 4);
    int*    rowPtr  = (int*)(ws + off);    off += align256((size_t)(N + 1) * 4);
    int*    bcur    = (int*)(ws + off);    off += align256((size_t)NBMAX * 4);
    int*    srcIdx  = (int*)(ws + off);    off += align256((size_t)E * 4);
    float*  region1 = (float*)(ws + off);  off += align256((size_t)N * 64 * 4);  // pairBuf, then z2
    float*  hT1     = (float*)(ws + off);  off += align256((size_t)N * 64 * 4);  // h~1 [N,64]
    float4* p       = (float4*)(ws + off); off += align256((size_t)N * 16);      // {x0,x1,dis,0}

    unsigned int* pairBuf = (unsigned int*)region1;  // 19.2 MB < 25.6 MB
    float* z2 = region1;                             // [N,64] (pairBuf dead by layer 2)

    const int B = 256;

    k_initcur<<<1, NBMAX, 0, stream>>>(bcur);
    {
        int nblk = (E + B * 32 - 1) / (B * 32);  // 391
        k_passA<<<nblk, B, 0, stream>>>(ei, bcur, pairBuf, E);
    }
    k_passB<<<NB, B, 0, stream>>>(bcur, pairBuf, rowPtr, dis, srcIdx, x, p, N, E);

    // layer 1: L2-resident p-gather + in-register feature recompute + fused @w1
    k_agg32x<<<(N * 64 + B - 1) / B, B, 0, stream>>>(rowPtr, srcIdx, p, w_node, b_node,
                                                     w1, b1, hT1, N);

    // layer 2: the pinned random-line service-bound gather
    k_agg64<<<(N * 64 + B - 1) / B, B, 0, stream>>>(rowPtr, srcIdx, hT1, dis, z2, N);

    // fused h2-compute + mean-pool + head
    k_poolhead<<<G, B, 0, stream>>>(z2, w2, b2, batch, wf1, bf1, wf2, bf2, out, N);
}

// Round 11
// 260.798 us; speedup vs baseline: 1.8246x; 1.1793x over previous
//
#include <hip/hip_runtime.h>
#include <hip/hip_fp16.h>

// ---------------------------------------------------------------------------
// GNN_20237885899323: 2-layer GCN + mean-pool + MLP head, fp32 compute.
// Round 11: h~1 stored as FP16 (accumulate fp32). agg64's random-row gather is
// pinned at ~104us / 362MB FETCH across 5 structural variants (line-service
// bound) -- the only lever left is bytes: rows 256B->128B, working set
// 25.6->12.8MB (per-XCD L2 residency ~16%->~31%, so FETCH should drop >2x).
// Error budget: fp16 rel 4.9e-4 on h~1~0.035 -> ~1.7e-5/elem, propagates to
// ~3e-6 at out vs 2.12e-4 threshold (70x margin). Everything else = round 10.
// ---------------------------------------------------------------------------

typedef float vfloat4 __attribute__((ext_vector_type(4)));

#define NBMAX 512
#define BCAP 12288
#define CAPL 10240

__global__ void k_initcur(int* __restrict__ bcur) {
    bcur[threadIdx.x] = threadIdx.x * BCAP;  // 512 threads
}

__global__ void k_passA(const int* __restrict__ ei, int* __restrict__ bcur,
                        unsigned int* __restrict__ pairBuf, int E) {
    __shared__ int h[NBMAX];
    __shared__ int base[NBMAX];
    const int T = 256, EPT = 32;
    int chunk = blockIdx.x * (T * EPT);
    int t = threadIdx.x;
    h[t] = 0; h[t + 256] = 0;
    __syncthreads();
    int nE = min(E - chunk, T * EPT);
    for (int i = t; i < nE; i += T)
        atomicAdd(&h[ei[E + chunk + i] >> 8], 1);
    __syncthreads();
    for (int bb = t; bb < NBMAX; bb += T) {
        int c = h[bb];
        base[bb] = c > 0 ? atomicAdd(&bcur[bb], c) : 0;
        h[bb] = 0;
    }
    __syncthreads();
    for (int i = t; i < nE; i += T) {
        int s = ei[chunk + i];
        int d = ei[E + chunk + i];
        int bb = d >> 8;
        int pos = base[bb] + atomicAdd(&h[bb], 1);
        pairBuf[pos] = ((unsigned int)(d & 255) << 24) | (unsigned int)s;  // cached: L2 merges
    }
}

// pass B: per-bucket counting sort -> rowPtr, dis, srcIdx, p={x0,x1,dis,0}
__global__ void k_passB(const int* __restrict__ bcur,
                        const unsigned int* __restrict__ pairBuf,
                        int* __restrict__ rowPtr, float* __restrict__ dis,
                        int* __restrict__ srcIdx, const float* __restrict__ x,
                        float4* __restrict__ p, int N, int E) {
    __shared__ unsigned int eLds[CAPL];
    __shared__ int hist[256];
    __shared__ int scan[256];
    int b = blockIdx.x;
    int t = threadIdx.x;  // 256
    int count = bcur[b] - b * BCAP;
    const unsigned int* src = pairBuf + (size_t)b * BCAP;
    int part = 0;
    for (int i = t; i < b; i += 256) part += bcur[i] - i * BCAP;
    scan[t] = part;
    __syncthreads();
    for (int o = 128; o > 0; o >>= 1) {
        if (t < o) scan[t] += scan[t + o];
        __syncthreads();
    }
    int gbase = scan[0];
    __syncthreads();
    hist[t] = 0;
    int nStage = min(count, CAPL);
    for (int i = t; i < nStage; i += 256) eLds[i] = __builtin_nontemporal_load(src + i);
    __syncthreads();
    for (int i = t; i < nStage; i += 256) atomicAdd(&hist[eLds[i] >> 24], 1);
    for (int i = CAPL + t; i < count; i += 256)
        atomicAdd(&hist[__builtin_nontemporal_load(src + i) >> 24], 1);
    __syncthreads();
    int c = hist[t];
    scan[t] = c;
    __syncthreads();
    for (int o = 1; o < 256; o <<= 1) {
        int v = (t >= o) ? scan[t - o] : 0;
        __syncthreads();
        scan[t] += v;
        __syncthreads();
    }
    int excl = scan[t] - c;
    int node = (b << 8) + t;
    float dval = rsqrtf((float)c + 1.0f);  // +1 self loop
    if (node < N) {
        rowPtr[node] = gbase + excl;
        dis[node] = dval;
        float4 pv;
        pv.x = x[2 * node]; pv.y = x[2 * node + 1]; pv.z = dval; pv.w = 0.f;
        p[node] = pv;
        if (node == N - 1) rowPtr[N] = E;
    }
    hist[t] = excl;
    __syncthreads();
    for (int i = t; i < nStage; i += 256) {
        unsigned int e = eLds[i];
        int pos = atomicAdd(&hist[e >> 24], 1);
        srcIdx[gbase + pos] = (int)(e & 0xFFFFFFu);  // cached: clustered, L2 merges
    }
    for (int i = CAPL + t; i < count; i += 256) {
        unsigned int e = __builtin_nontemporal_load(src + i);
        int pos = atomicAdd(&hist[e >> 24], 1);
        srcIdx[gbase + pos] = (int)(e & 0xFFFFFFu);
    }
}

// layer 1: gather p[src] (16B, 1.6MB = L2-resident), recompute h~0 features
// in-register; butterfly reduce; fused @w1 epilogue. Output h~1 in FP16.
__global__ void k_agg32x(const int* __restrict__ rowPtr, const int* __restrict__ srcIdx,
                         const float4* __restrict__ p, const float* __restrict__ wn,
                         const float* __restrict__ bn, const float* __restrict__ w1,
                         const float* __restrict__ b1, __half* __restrict__ hOut, int N) {
    constexpr int RPI = 8, U = 4, CH = RPI * U;
    int wid = (blockIdx.x * blockDim.x + threadIdx.x) >> 6;
    if (wid >= N) return;
    int lane = threadIdx.x & 63;
    int q = lane & 7;   // feature quad: f = 4q..4q+3
    int r = lane >> 3;  // row group 0..7
    float wn0[4], wn1[4], bnv[4];
#pragma unroll
    for (int j = 0; j < 4; ++j) {
        wn0[j] = wn[4 * q + j];
        wn1[j] = wn[32 + 4 * q + j];
        bnv[j] = bn[4 * q + j];
    }
    float4 pd = p[wid];
    float accv[4] = {0.f, 0.f, 0.f, 0.f};
    if (r == 0) {  // self loop
#pragma unroll
        for (int j = 0; j < 4; ++j) {
            float v = fmaf(pd.x, wn0[j], fmaf(pd.y, wn1[j], bnv[j]));
            accv[j] = fmaxf(v, 0.f) * pd.z;
        }
    }
    int beg = rowPtr[wid], end = rowPtr[wid + 1];
    if (end > beg) {
        int last = end - 1;
        for (int base = beg; base < end; base += CH) {
            int s[U];
            float m[U];
#pragma unroll
            for (int u = 0; u < U; ++u) {
                int i = base + r + u * RPI;
                m[u] = (i < end) ? 1.f : 0.f;
                s[u] = __builtin_nontemporal_load(srcIdx + min(i, last));
            }
            float4 ps[U];
#pragma unroll
            for (int u = 0; u < U; ++u) ps[u] = p[s[u]];
#pragma unroll
            for (int u = 0; u < U; ++u) {
                float scale = ps[u].z * m[u];
#pragma unroll
                for (int j = 0; j < 4; ++j) {
                    float v = fmaf(ps[u].x, wn0[j], fmaf(ps[u].y, wn1[j], bnv[j]));
                    accv[j] = fmaf(fmaxf(v, 0.f), scale, accv[j]);
                }
            }
        }
    }
#pragma unroll
    for (int mk = 8; mk < 64; mk <<= 1) {
#pragma unroll
        for (int j = 0; j < 4; ++j) accv[j] += __shfl_xor(accv[j], mk);
    }
    int f = lane;
    float s = 0.f;
#pragma unroll
    for (int q2 = 0; q2 < 8; ++q2) {
#pragma unroll
        for (int j = 0; j < 4; ++j) {
            float bv = __shfl(accv[j], q2);
            s = fmaf(bv, w1[(4 * q2 + j) * 64 + f], s);
        }
    }
    float dv = pd.z;
    float h = fmaxf(fmaf(dv, s, b1[f]), 0.f) * dv;
    hOut[(size_t)wid * 64 + f] = __float2half(h);
}

// layer 2 aggregation over FP16 rows (128 B): one wave per dst node.
// q = 16B chunk (8 halves), r = row group 0..7; fp32 accumulate; fp32 z out.
__global__ void k_agg64h(const int* __restrict__ rowPtr, const int* __restrict__ srcIdx,
                         const __half* __restrict__ y, const float* __restrict__ dis,
                         float* __restrict__ z, int N) {
    constexpr int RPI = 8, U = 4, CH = RPI * U;  // 32 rows per iter
    int wid = (blockIdx.x * blockDim.x + threadIdx.x) >> 6;
    if (wid >= N) return;
    int lane = threadIdx.x & 63;
    int q = lane & 7;   // 16-byte chunk: features 8q..8q+7
    int r = lane >> 3;  // row group 0..7
    const float4* yq = (const float4*)y;  // one row = 8 float4 (64 halves)
    float acc[8] = {0.f, 0.f, 0.f, 0.f, 0.f, 0.f, 0.f, 0.f};
    if (r == 0) {  // self row
        float4 a = yq[(size_t)wid * 8 + q];
        union { float4 f4; __half2 h2[4]; } cv; cv.f4 = a;
#pragma unroll
        for (int j = 0; j < 4; ++j) {
            float2 f = __half22float2(cv.h2[j]);
            acc[2 * j] = f.x; acc[2 * j + 1] = f.y;
        }
    }
    int beg = rowPtr[wid], end = rowPtr[wid + 1];
    if (end > beg) {
        int last = end - 1;
        for (int base = beg; base < end; base += CH) {
            int s[U];
            float m[U];
#pragma unroll
            for (int u = 0; u < U; ++u) {
                int i = base + r + u * RPI;
                m[u] = (i < end) ? 1.f : 0.f;
                s[u] = __builtin_nontemporal_load(srcIdx + min(i, last));
            }
#pragma unroll
            for (int u = 0; u < U; ++u) {
                float4 a = yq[(size_t)s[u] * 8 + q];
                union { float4 f4; __half2 h2[4]; } cv; cv.f4 = a;
#pragma unroll
                for (int j = 0; j < 4; ++j) {
                    float2 f = __half22float2(cv.h2[j]);
                    acc[2 * j]     = fmaf(f.x, m[u], acc[2 * j]);
                    acc[2 * j + 1] = fmaf(f.y, m[u], acc[2 * j + 1]);
                }
            }
        }
    }
#pragma unroll
    for (int mk = 8; mk < 64; mk <<= 1) {
#pragma unroll
        for (int j = 0; j < 8; ++j) acc[j] += __shfl_xor(acc[j], mk);
    }
    if (r == 0) {
        float dv = dis[wid];
        float4 o0 = {acc[0] * dv, acc[1] * dv, acc[2] * dv, acc[3] * dv};
        float4 o1 = {acc[4] * dv, acc[5] * dv, acc[6] * dv, acc[7] * dv};
        float4* zp = (float4*)(z + (size_t)wid * 64 + q * 8);
        zp[0] = o0;  // plain store: stays in L2 for poolhead
        zp[1] = o1;
    }
}

// block-per-graph (256 thr): binary-search node range in sorted batch;
// h2 = relu(z2@w2+b2) on the fly (w2 column in VGPRs); mean; MLP head.
__global__ void k_poolhead(const float* __restrict__ z2, const float* __restrict__ w2,
                           const float* __restrict__ b2, const int* __restrict__ batch,
                           const float* __restrict__ wf1, const float* __restrict__ bf1,
                           const float* __restrict__ wf2, const float* __restrict__ bf2,
                           float* __restrict__ out, int N) {
    __shared__ float red[4][64];
    __shared__ float pooled[64];
    __shared__ float gv[32];
    __shared__ int range[2];
    int g = blockIdx.x;
    int t = threadIdx.x;  // 256
    if (t < 2) {
        int target = g + t;
        int lo = 0, hi = N;
        while (lo < hi) {
            int mid = (lo + hi) >> 1;
            if (batch[mid] < target) lo = mid + 1; else hi = mid;
        }
        range[t] = lo;
    }
    __syncthreads();
    int s = range[0], e = range[1];
    int w = t >> 6, f = t & 63;
    float wcol[64];
#pragma unroll
    for (int k = 0; k < 64; ++k) wcol[k] = w2[k * 64 + f];
    float bf = b2[f];
    float acc = 0.f;
    for (int n = s + w; n < e; n += 4) {
        const float4* zr = (const float4*)(z2 + (size_t)n * 64);
        float h = bf;
#pragma unroll
        for (int kq = 0; kq < 16; ++kq) {
            float4 zv = zr[kq];
            h += zv.x * wcol[4 * kq + 0];
            h += zv.y * wcol[4 * kq + 1];
            h += zv.z * wcol[4 * kq + 2];
            h += zv.w * wcol[4 * kq + 3];
        }
        acc += fmaxf(h, 0.f);
    }
    red[w][f] = acc;
    __syncthreads();
    if (t < 64) {
        float c = (float)(e - s);
        c = c > 1.f ? c : 1.f;
        pooled[t] = (red[0][t] + red[1][t] + red[2][t] + red[3][t]) / c;
    }
    __syncthreads();
    if (t < 32) {
        float sv = bf1[t];
#pragma unroll
        for (int k = 0; k < 64; ++k) sv += pooled[k] * wf1[k * 32 + t];
        gv[t] = fmaxf(sv, 0.f);
    }
    __syncthreads();
    if (t == 0) {
        float sv = bf2[0];
#pragma unroll
        for (int j = 0; j < 32; ++j) sv += gv[j] * wf2[j];
        out[g] = sv;
    }
}

extern "C" void kernel_launch(void* const* d_in, const int* in_sizes, int n_in,
                              void* d_out, int out_size, void* d_ws, size_t ws_size,
                              hipStream_t stream) {
    const float* x      = (const float*)d_in[0];
    const int*   ei     = (const int*)d_in[2];
    const int*   batch  = (const int*)d_in[3];
    const float* w_node = (const float*)d_in[4];
    const float* b_node = (const float*)d_in[5];
    const float* w1  = (const float*)d_in[8];
    const float* b1  = (const float*)d_in[9];
    const float* w2  = (const float*)d_in[10];
    const float* b2  = (const float*)d_in[11];
    const float* wf1 = (const float*)d_in[12];
    const float* bf1 = (const float*)d_in[13];
    const float* wf2 = (const float*)d_in[14];
    const float* bf2 = (const float*)d_in[15];
    float* out = (float*)d_out;

    const int N = in_sizes[0] / 2;  // 100000
    const int E = in_sizes[2] / 2;  // 3200000
    const int G = out_size;         // 1024
    const int NB = (N + 255) >> 8;  // 391

    auto align256 = [](size_t v) { return (v + 255) & ~(size_t)255; };
    char* ws = (char*)d_ws;
    size_t off = 0;
    float*  dis     = (float*)(ws + off);  off += align256((size_t)N * 4);
    int*    rowPtr  = (int*)(ws + off);    off += align256((size_t)(N + 1) * 4);
    int*    bcur    = (int*)(ws + off);    off += align256((size_t)NBMAX * 4);
    int*    srcIdx  = (int*)(ws + off);    off += align256((size_t)E * 4);
    float*  region1 = (float*)(ws + off);  off += align256((size_t)N * 64 * 4);  // pairBuf, then z2
    __half* hT1     = (__half*)(ws + off); off += align256((size_t)N * 64 * 2);  // h~1 [N,64] fp16
    float4* p       = (float4*)(ws + off); off += align256((size_t)N * 16);      // {x0,x1,dis,0}

    unsigned int* pairBuf = (unsigned int*)region1;  // 19.2 MB < 25.6 MB
    float* z2 = region1;                             // [N,64] fp32 (pairBuf dead by layer 2)

    const int B = 256;

    k_initcur<<<1, NBMAX, 0, stream>>>(bcur);
    {
        int nblk = (E + B * 32 - 1) / (B * 32);  // 391
        k_passA<<<nblk, B, 0, stream>>>(ei, bcur, pairBuf, E);
    }
    k_passB<<<NB, B, 0, stream>>>(bcur, pairBuf, rowPtr, dis, srcIdx, x, p, N, E);

    // layer 1: L2-resident p-gather + in-register feature recompute + fused @w1 -> fp16 h~1
    k_agg32x<<<(N * 64 + B - 1) / B, B, 0, stream>>>(rowPtr, srcIdx, p, w_node, b_node,
                                                     w1, b1, hT1, N);

    // layer 2: fp16-row gather (128 B/row, 12.8 MB working set)
    k_agg64h<<<(N * 64 + B - 1) / B, B, 0, stream>>>(rowPtr, srcIdx, hT1, dis, z2, N);

    // fused h2-compute + mean-pool + head
    k_poolhead<<<G, B, 0, stream>>>(z2, w2, b2, batch, wf1, bf1, wf2, bf2, out, N);
}